// Round 8
// baseline (519.740 us; speedup 1.0000x reference)
//
#include <hip/hip_runtime.h>
#include <stdint.h>

// ---------------------------------------------------------------------------
// Qwen2-7B attention block on gfx950.
// R15: attn de-staged (m169 precedent: drop LDS staging when K/V L2-fits).
//   R13/R14 post-mortem: VALU diet, swizzles, occupancy all null -> the
//   4-wave lockstep barrier+staging chain IS the bound (~65us idle).
//   - K frags: ld_frag direct from global (same pattern as Q frags; 4 waves
//     hit identical addresses -> L1). V: one-shot vt_kernel writes
//     Vt[kvh*128+d][kv] (2MB) after gemm1; PV reads V^T frags from global.
//   - attn has NO barriers, no kvK/kvV, no kreg/vreg; LDS = pb only (18KB,
//     per-wave private). setprio now meaningful (independent waves, m191).
//   - vf loads batched 4-wide to bound VGPR; no launch_bounds min-wave arg
//     (R10 spill lesson).
//   Fallback (small-ws) path keeps the R14 LDS-staged attn unchanged.
// GEMMs (BN=192/128 8-phase), RoPE, dequant unchanged.
// ---------------------------------------------------------------------------

typedef short vshort4 __attribute__((ext_vector_type(4)));
typedef short vshort8 __attribute__((ext_vector_type(8)));
typedef __bf16 vbf16x4 __attribute__((ext_vector_type(4)));
typedef __bf16 vbf16x8 __attribute__((ext_vector_type(8)));
typedef float vfloat4 __attribute__((ext_vector_type(4)));

#define SEQ 2048
#define NH 28
#define KVH 4
#define HD 128
#define QSZ 3584
#define QKV_N 4608
#define SM_SCALE 0.08838834764831845f
#define SM_LOG2E 0.1275174331f   /* SM_SCALE * log2(e) */

__device__ __forceinline__ float bf2f(unsigned short h) {
  union { unsigned int u; float f; } x; x.u = ((unsigned int)h) << 16; return x.f;
}
__device__ __forceinline__ unsigned short f2bf(float f) {
  union { unsigned int u; float f; } x; x.f = f;
  x.u += 0x7fff + ((x.u >> 16) & 1);
  return (unsigned short)(x.u >> 16);
}
__device__ __forceinline__ vbf16x8 ld_frag(const unsigned short* p) {
  return __builtin_bit_cast(vbf16x8, *(const vshort8*)p);
}
__device__ __forceinline__ vfloat4 mfma16(vbf16x8 a, vbf16x8 b, vfloat4 c) {
  return __builtin_amdgcn_mfma_f32_16x16x32_bf16(a, b, c, 0, 0, 0);
}
__device__ __forceinline__ void async_cp16(const unsigned short* g, unsigned short* l) {
  __builtin_amdgcn_global_load_lds((const __attribute__((address_space(1))) void*)g,
                                   (__attribute__((address_space(3))) void*)l, 16, 0, 0);
}
__device__ __forceinline__ vshort4 pack4f(float a, float b, float c, float d) {
  vbf16x4 t; t[0] = (__bf16)a; t[1] = (__bf16)b; t[2] = (__bf16)c; t[3] = (__bf16)d;
  return __builtin_bit_cast(vshort4, t);
}

// ---------------------------------------------------------------------------
__global__ __launch_bounds__(256) void detect_dtype(
    const unsigned short* __restrict__ h, int* __restrict__ flag)
{
  __shared__ int red[256];
  int cnt = 0;
#pragma unroll
  for (int i = 0; i < 8; ++i) {
    unsigned short u = h[threadIdx.x * 8 + i];
    int e = (u >> 7) & 0xFF;
    cnt += (e >= 100 && e <= 150) ? 1 : 0;
  }
  red[threadIdx.x] = cnt;
  __syncthreads();
  for (int s = 128; s > 0; s >>= 1) {
    if (threadIdx.x < s) red[threadIdx.x] += red[threadIdx.x + s];
    __syncthreads();
  }
  if (threadIdx.x == 0) flag[0] = (red[0] >= 1700) ? 1 : 0;
}

__global__ __launch_bounds__(256) void convert_bf(
    const void* __restrict__ src, unsigned short* __restrict__ dst,
    const int* __restrict__ flag)
{
  int i = blockIdx.x * 256 + threadIdx.x;
  if (flag[0]) dst[i] = ((const unsigned short*)src)[i];
  else         dst[i] = f2bf(((const float*)src)[i]);
}

__global__ __launch_bounds__(256) void convert_bf8(
    const void* __restrict__ src, unsigned short* __restrict__ dst,
    const int* __restrict__ flag)
{
  int i = (blockIdx.x * 256 + threadIdx.x) * 8;
  if (flag[0]) {
    *(vshort8*)(dst + i) = *(const vshort8*)((const unsigned short*)src + i);
  } else {
    const float* s = (const float*)src + i;
    float4 a = *(const float4*)s;
    float4 b = *(const float4*)(s + 4);
    vshort8 o;
    o[0] = (short)f2bf(a.x); o[1] = (short)f2bf(a.y);
    o[2] = (short)f2bf(a.z); o[3] = (short)f2bf(a.w);
    o[4] = (short)f2bf(b.x); o[5] = (short)f2bf(b.y);
    o[6] = (short)f2bf(b.z); o[7] = (short)f2bf(b.w);
    *(vshort8*)(dst + i) = o;
  }
}

// ---------------------------------------------------------------------------
__global__ __launch_bounds__(256) void dequant_awq(
    const int* __restrict__ qw, const int* __restrict__ qz,
    const unsigned short* __restrict__ scales,
    unsigned short* __restrict__ Wt,
    int Kdim, int CwChunk, int CwStride, int NoutStride)
{
  int idx = blockIdx.x * 256 + threadIdx.x;   // total = (Kdim/4)*CwChunk
  int kq = Kdim >> 2;
  int k4 = idx % kq;
  int c  = idx / kq;
  int k  = k4 * 4;
  int g  = k >> 7;
  int w0 = qw[(size_t)(k + 0) * CwStride + c];
  int w1 = qw[(size_t)(k + 1) * CwStride + c];
  int w2 = qw[(size_t)(k + 2) * CwStride + c];
  int w3 = qw[(size_t)(k + 3) * CwStride + c];
  int z  = qz[(size_t)g * CwStride + c];
#pragma unroll
  for (int j = 0; j < 8; ++j) {
    int sh = 4 * j;
    float zn = (float)((z >> sh) & 0xF);
    float s  = bf2f(scales[(size_t)g * NoutStride + c * 8 + j]);
    vshort4 o;
    o[0] = (short)f2bf(((float)((w0 >> sh) & 0xF) - zn) * s);
    o[1] = (short)f2bf(((float)((w1 >> sh) & 0xF) - zn) * s);
    o[2] = (short)f2bf(((float)((w2 >> sh) & 0xF) - zn) * s);
    o[3] = (short)f2bf(((float)((w3 >> sh) & 0xF) - zn) * s);
    *(vshort4*)(Wt + (size_t)(c * 8 + j) * Kdim + k) = o;
  }
}

// ---------------------------------------------------------------------------
// 8-phase 256-row GEMM.  C[m0..m0+256][n0..n0+BN] += A[256xK] * Bt[BNxK]^T.
// ---------------------------------------------------------------------------
#define BAR()   asm volatile("s_barrier" ::: "memory")
#define LGKM0() asm volatile("s_waitcnt lgkmcnt(0)" ::: "memory")

template<int BN>
__global__ __launch_bounds__(512, 2) void gemm8p(
    const unsigned short* __restrict__ A,
    const unsigned short* __restrict__ Bt,
    const unsigned short* __restrict__ bias,
    void* __restrict__ Cv, int n_base, int ldc, int K,
    const int* __restrict__ oflag)
{
  constexpr int HB  = (BN / 2) * 64;     // half of B region (B region = BN*64)
  constexpr int HA  = 128 * 64;          // A-half elems
  constexpr int GRP = 2 * HB + 2 * HA;   // one K-tile group
  constexpr int NC  = BN / 64;           // col frags per wave (4 / 3 / 2)
  constexpr int CH  = NC / 2;            // (not used by BN=192 path)
  __shared__ __align__(16) unsigned short lds[2 * GRP];

  const int tid = threadIdx.x;
  const int w = tid >> 6, lane = tid & 63;
  const int c16 = lane & 15, q4 = lane >> 4;
  const int wm = w >> 2, wn = w & 3;
  const int m0 = blockIdx.y * 256, n0 = blockIdx.x * BN;

  // staging: linear LDS dest, inverse-swizzled global source (16B slot ^ row&7)
  const int srow = tid >> 3;
  const int scol = ((tid & 7) ^ (srow & 7)) * 8;
  const unsigned short* const aS = A  + (size_t)(m0 + srow) * K + scol;
  const unsigned short* const bS = Bt + (size_t)(n0 + srow) * K + scol;
  const int wst = w * 512;               // wave slot within each 8KB sweep

  // swizzled ds_read offsets (elements)
  int offA[4][2], offB[NC][2];
  const int swz = c16 & 7;
#pragma unroll
  for (int kh = 0; kh < 2; ++kh) {
    const int ko = ((kh * 4 + q4) ^ swz) * 8;
#pragma unroll
    for (int i = 0; i < 4; ++i) offA[i][kh] = (i * 16 + c16) * 64 + ko;
#pragma unroll
    for (int cj = 0; cj < NC; ++cj)
      offB[cj][kh] = ((wn & 1) * (BN / 4) + cj * 16 + c16) * 64 + ko;
  }
  const int aB0 = 2 * HB + wm * HA;
  const int bB0 = (wn >> 1) * HB;

  vbf16x8 af[4][2], bfr[NC][2];
  vfloat4 acc[8][NC];
#pragma unroll
  for (int i = 0; i < 8; ++i)
#pragma unroll
    for (int c = 0; c < NC; ++c) { vfloat4 z = {0.f, 0.f, 0.f, 0.f}; acc[i][c] = z; }

#define LD_A(g_, rh_) do { \
    const unsigned short* p_ = lds + (g_) * GRP + aB0 + (rh_) * 4096; \
    _Pragma("unroll") for (int i_ = 0; i_ < 4; ++i_) { \
      af[i_][0] = ld_frag(p_ + offA[i_][0]); af[i_][1] = ld_frag(p_ + offA[i_][1]); } } while (0)
#define MMg(rb_, c0_, cn_) do { \
    __builtin_amdgcn_s_setprio(1); \
    _Pragma("unroll") for (int i_ = 0; i_ < 4; ++i_) \
    _Pragma("unroll") for (int c_ = 0; c_ < (cn_); ++c_) { \
      acc[(rb_) + i_][(c0_) + c_] = mfma16(af[i_][0], bfr[(c0_) + c_][0], acc[(rb_) + i_][(c0_) + c_]); \
      acc[(rb_) + i_][(c0_) + c_] = mfma16(af[i_][1], bfr[(c0_) + c_][1], acc[(rb_) + i_][(c0_) + c_]); } \
    __builtin_amdgcn_s_setprio(0); } while (0)

  const int nT  = K >> 6;
  const int nIt = nT >> 1;

  if constexpr (BN == 192) {
    // ---- sweep staging: 1 cp16/thread each; B=3 sweeps, A=4 sweeps ----
#define SWB(g_, s_, t_) async_cp16(bS + (size_t)(s_) * 64 * K + (size_t)(t_) * 64, \
                                   lds + (g_) * GRP + (s_) * 4096 + wst)
#define SWA(g_, s_, t_) async_cp16(aS + (size_t)(s_) * 64 * K + (size_t)(t_) * 64, \
                                   lds + (g_) * GRP + 2 * HB + (s_) * 4096 + wst)
#define LDB01(g_) do { const unsigned short* p_ = lds + (g_) * GRP + bB0; \
    bfr[0][0] = ld_frag(p_ + offB[0][0]); bfr[0][1] = ld_frag(p_ + offB[0][1]); \
    bfr[1][0] = ld_frag(p_ + offB[1][0]); bfr[1][1] = ld_frag(p_ + offB[1][1]); } while (0)
#define LDB2(g_) do { const unsigned short* p_ = lds + (g_) * GRP + bB0; \
    bfr[2][0] = ld_frag(p_ + offB[2][0]); bfr[2][1] = ld_frag(p_ + offB[2][1]); } while (0)
#define VM2() asm volatile("s_waitcnt vmcnt(2)" ::: "memory")

    // prologue: tile0 full (7 sweeps), tile1 B0,B1
    SWB(0, 0, 0); SWB(0, 1, 0); SWB(0, 2, 0);
    SWA(0, 0, 0); SWA(0, 1, 0); SWA(0, 2, 0); SWA(0, 3, 0);
    SWB(1, 0, 1); SWB(1, 1, 1);
    VM2(); BAR();

    for (int it = 0; it < nIt - 1; ++it) {
      const int tO = 2 * it + 1, tE2 = 2 * it + 2, tO2 = 2 * it + 3;
      // ph0: read grp0 A rows0-3 + B cols0-1; stage O tail
      LD_A(0, 0); LDB01(0);
      SWB(1, 2, tO); SWA(1, 0, tO);
      BAR(); LGKM0(); MMg(0, 0, 2); BAR();
      // ph1
      LDB2(0);
      SWA(1, 1, tO); SWA(1, 2, tO);
      BAR(); LGKM0(); MMg(0, 2, 1); BAR();
      // ph2
      LD_A(0, 1);
      SWA(1, 3, tO);
      BAR(); LGKM0(); MMg(4, 0, 2); BAR();
      // ph3: grp0 free after ph2 bar; start E2; drain O (only E2.B0/B1 newer)
      SWB(0, 0, tE2); SWB(0, 1, tE2);
      VM2(); BAR(); MMg(4, 2, 1); BAR();
      // ph4
      LD_A(1, 0); LDB01(1);
      SWB(0, 2, tE2); SWA(0, 0, tE2);
      BAR(); LGKM0(); MMg(0, 0, 2); BAR();
      // ph5
      LDB2(1);
      SWA(0, 1, tE2); SWA(0, 2, tE2);
      BAR(); LGKM0(); MMg(0, 2, 1); BAR();
      // ph6
      LD_A(1, 1);
      SWA(0, 3, tE2);
      BAR(); LGKM0(); MMg(4, 0, 2); BAR();
      // ph7: start O2; drain E2 (only O2.B0/B1 newer)
      SWB(1, 0, tO2); SWB(1, 1, tO2);
      VM2(); BAR(); MMg(4, 2, 1); BAR();
    }

    // peeled: grp0 = tile nT-2 (fully staged); grp1 = tile nT-1 (B0,B1 staged)
    {
      const int tO = nT - 1;
      LD_A(0, 0); LDB01(0);
      SWB(1, 2, tO); SWA(1, 0, tO);
      BAR(); LGKM0(); MMg(0, 0, 2); BAR();
      LDB2(0);
      SWA(1, 1, tO); SWA(1, 2, tO);
      BAR(); LGKM0(); MMg(0, 2, 1); BAR();
      LD_A(0, 1);
      SWA(1, 3, tO);
      BAR(); LGKM0(); MMg(4, 0, 2); BAR();
      asm volatile("s_waitcnt vmcnt(0)" ::: "memory");
      BAR(); MMg(4, 2, 1);
      LD_A(1, 0); LDB01(1); LDB2(1);
      LGKM0(); MMg(0, 0, 2); MMg(0, 2, 1);
      LD_A(1, 1);
      LGKM0(); MMg(4, 0, 2); MMg(4, 2, 1);
    }
#undef SWB
#undef SWA
#undef LDB01
#undef LDB2
#undef VM2
  } else {
    // ---- BN=256 / BN=128 path (verified in R8, unchanged) ----
#define STG_A(g_, h_, t_) do { \
    const unsigned short* s_ = aS + (size_t)(h_) * 128 * K + (size_t)(t_) * 64; \
    unsigned short* d_ = lds + (g_) * GRP + 2 * HB + (h_) * HA + wst; \
    async_cp16(s_, d_); async_cp16(s_ + (size_t)64 * K, d_ + 4096); } while (0)
#define STG_B(g_, h_, t_) do { \
    const unsigned short* s_ = bS + (size_t)(h_) * (BN / 2) * K + (size_t)(t_) * 64; \
    unsigned short* d_ = lds + (g_) * GRP + (h_) * HB + wst; \
    async_cp16(s_, d_); \
    if constexpr (BN == 256) async_cp16(s_ + (size_t)64 * K, d_ + 4096); } while (0)
#define VMW() do { if constexpr (BN == 256) asm volatile("s_waitcnt vmcnt(6)" ::: "memory"); \
                   else                     asm volatile("s_waitcnt vmcnt(4)" ::: "memory"); } while (0)
#define LD_B(g_) do { \
    const unsigned short* p_ = lds + (g_) * GRP + bB0; \
    _Pragma("unroll") for (int c_ = 0; c_ < NC; ++c_) { \
      bfr[c_][0] = ld_frag(p_ + offB[c_][0]); bfr[c_][1] = ld_frag(p_ + offB[c_][1]); } } while (0)

    // prologue: tile0 full, tile1 B0,B1,A0
    STG_B(0, 0, 0); STG_B(0, 1, 0); STG_A(0, 0, 0); STG_A(0, 1, 0);
    STG_B(1, 0, 1); STG_B(1, 1, 1); STG_A(1, 0, 1);
    VMW(); BAR();

    for (int it = 0; it < nIt - 1; ++it) {
      const int tE = 2 * it + 2, tO = 2 * it + 3;
      // ph0
      LD_A(0, 0); LD_B(0);
      STG_A(1, 1, tO - 2);
      BAR(); LGKM0(); MMg(0, 0, CH); BAR();
      // ph1
      STG_B(0, 0, tE);
      BAR(); LGKM0(); MMg(0, CH, CH); BAR();
      // ph2
      LD_A(0, 1);
      STG_B(0, 1, tE);
      BAR(); LGKM0(); MMg(4, 0, CH); BAR();
      // ph3
      STG_A(0, 0, tE);
      VMW(); BAR(); LGKM0(); MMg(4, CH, CH); BAR();
      // ph4
      LD_A(1, 0); LD_B(1);
      STG_A(0, 1, tE);
      BAR(); LGKM0(); MMg(0, 0, CH); BAR();
      // ph5
      STG_B(1, 0, tO);
      BAR(); LGKM0(); MMg(0, CH, CH); BAR();
      // ph6
      LD_A(1, 1);
      STG_B(1, 1, tO);
      BAR(); LGKM0(); MMg(4, 0, CH); BAR();
      // ph7
      STG_A(1, 0, tO);
      VMW(); BAR(); LGKM0(); MMg(4, CH, CH); BAR();
    }

    // peeled last iteration
    LD_A(0, 0); LD_B(0);
    STG_A(1, 1, nT - 1);
    BAR(); LGKM0();
    MMg(0, 0, CH); MMg(0, CH, CH);
    LD_A(0, 1);
    LGKM0();
    MMg(4, 0, CH); MMg(4, CH, CH);
    asm volatile("s_waitcnt vmcnt(0)" ::: "memory");
    BAR();
    LD_A(1, 0); LD_B(1);
    MMg(0, 0, CH); MMg(0, CH, CH);
    LD_A(1, 1);
    LGKM0();
    MMg(4, 0, CH); MMg(4, CH, CH);
#undef STG_A
#undef STG_B
#undef VMW
#undef LD_B
  }

  // ---- epilogue ----
  const int bfm = (oflag == nullptr) ? 1 : oflag[0];
#pragma unroll
  for (int ri = 0; ri < 8; ++ri) {
    const int m = m0 + wm * 128 + ri * 16 + q4 * 4;
#pragma unroll
    for (int cj = 0; cj < NC; ++cj) {
      const int n = n0 + wn * (BN / 4) + cj * 16 + c16;
      const float bv = bias ? bf2f(bias[n]) : 0.f;
#pragma unroll
      for (int r = 0; r < 4; ++r) {
        const float v = acc[ri][cj][r] + bv;
        const size_t idx = (size_t)(m + r) * ldc + n + n_base;
        if (bfm) ((unsigned short*)Cv)[idx] = f2bf(v);
        else     ((float*)Cv)[idx] = v;
      }
    }
  }
#undef LD_A
#undef MMg
}

// ---------------------------------------------------------------------------
// RoPE: precompute sincos table [SEQ][64] (float2), then vectorized apply.
// ---------------------------------------------------------------------------
__global__ __launch_bounds__(256) void rope_table(
    const int* __restrict__ pos, float2* __restrict__ tbl)
{
  int idx = blockIdx.x * 256 + threadIdx.x;  // SEQ*64 = 131072
  int j = idx & 63, s = idx >> 6;
  float inv = exp2f(-(float)j * 0.31143079014569017f);  // 1e6^(-j/64)
  float ang = (float)pos[s] * inv;
  float sn, cs;
  sincosf(ang, &sn, &cs);
  tbl[idx] = make_float2(cs, sn);
}

__global__ __launch_bounds__(256) void rope_apply(
    unsigned short* __restrict__ qkv, const float2* __restrict__ tbl)
{
  int idx = blockIdx.x * 256 + threadIdx.x;  // SEQ*32*16 = 1048576
  int j4 = idx & 15;
  int h2 = (idx >> 4) & 31;
  int s = idx >> 9;
  int jb = j4 * 4;
  unsigned short* row = qkv + (size_t)s * QKV_N
                        + ((h2 < NH) ? h2 * HD : QSZ + (h2 - NH) * HD);
  vshort4 x1 = *(const vshort4*)(row + jb);
  vshort4 x2 = *(const vshort4*)(row + jb + 64);
  const float2* tp = tbl + s * 64 + jb;
  vshort4 o1, o2;
#pragma unroll
  for (int q = 0; q < 4; ++q) {
    float2 cn = tp[q];
    float a = bf2f((unsigned short)x1[q]);
    float b = bf2f((unsigned short)x2[q]);
    o1[q] = (short)f2bf(a * cn.x - b * cn.y);
    o2[q] = (short)f2bf(b * cn.x + a * cn.y);
  }
  *(vshort4*)(row + jb) = o1;
  *(vshort4*)(row + jb + 64) = o2;
}

// ---------------------------------------------------------------------------
// V transpose: Vt[kvh*128+d][kv] from qkvb V region (V needs no RoPE).
// grid (32, 8): 64(s) x 64(d) tiles. 2MB total.
// ---------------------------------------------------------------------------
__global__ __launch_bounds__(256) void vt_kernel(
    const unsigned short* __restrict__ qkv, unsigned short* __restrict__ Vt)
{
  __shared__ unsigned short tile[64][72];
  const int s0 = blockIdx.x * 64;
  const int dg = blockIdx.y * 64;          // global index into [0,512)
  const int kvh = dg >> 7, d0 = dg & 127;
  const int tid = threadIdx.x;
#pragma unroll
  for (int it = 0; it < 2; ++it) {
    int row = it * 32 + (tid >> 3);
    int dc = (tid & 7) * 8;
    *(vshort8*)&tile[row][dc] =
        *(const vshort8*)(qkv + (size_t)(s0 + row) * QKV_N + QSZ + 512
                          + kvh * HD + d0 + dc);
  }
  __syncthreads();
#pragma unroll
  for (int it = 0; it < 2; ++it) {
    int dr = it * 32 + (tid >> 3);
    int sc = (tid & 7) * 8;
    vshort8 o;
#pragma unroll
    for (int e = 0; e < 8; ++e) o[e] = (short)tile[sc + e][dr];
    *(vshort8*)(Vt + (size_t)(dg + dr) * SEQ + s0 + sc) = o;
  }
}

// ---------------------------------------------------------------------------
// GQA causal flash attention, de-staged: K/V frags direct from global (L1/L2
// cached; m169 precedent). No barriers; LDS = per-wave pb only.
// ---------------------------------------------------------------------------
__global__ __launch_bounds__(256) void attn_kernel(
    const unsigned short* __restrict__ qkv,
    const unsigned short* __restrict__ Vt,
    unsigned short* __restrict__ attnb,
    unsigned short* __restrict__ part1,
    float* __restrict__ ml)
{
  __shared__ __align__(16) unsigned short pb[4 * 32 * 72];
  const int tid = threadIdx.x, w = tid >> 6, lane = tid & 63;
  const int c16 = lane & 15, q4 = lane >> 4;

  int bid = blockIdx.x;
  int h, qt, chunk, kt0, kt1, t = 0;
  if (bid < 448) {
    h = bid >> 4; int s = bid & 15;
    qt = 15 - (s >> 1); chunk = s & 1;
    int half = qt + 1;
    kt0 = chunk * half; kt1 = kt0 + half;
    t = h * 8 + (qt - 8);
  } else {
    int d = bid - 448; h = d >> 3; qt = 7 - (d & 7); chunk = -1;
    kt0 = 0; kt1 = 2 * (qt + 1);
  }
  const int q0 = qt * 128;
  const int kvh = h / 7;
  unsigned short* pw = pb + w * 2304;
  const unsigned short* const Kb = qkv + QSZ + kvh * HD + q4 * 8;   // + row*QKV_N + kk*32
  const unsigned short* const Vb = Vt + (size_t)(kvh * 128 + c16) * SEQ + q4 * 8;

  vbf16x8 qf[2][4];
#pragma unroll
  for (int i = 0; i < 2; ++i)
#pragma unroll
    for (int kk = 0; kk < 4; ++kk)
      qf[i][kk] = ld_frag(qkv + (size_t)(q0 + w * 32 + i * 16 + c16) * QKV_N
                          + h * HD + kk * 32 + q4 * 8);

  vfloat4 of[2][8];
  vfloat4 ofl[2];
  float m_run[2];
#pragma unroll
  for (int i = 0; i < 2; ++i) {
    m_run[i] = -1e30f;
    vfloat4 z = {0.f, 0.f, 0.f, 0.f};
    ofl[i] = z;
#pragma unroll
    for (int j = 0; j < 8; ++j) of[i][j] = z;
  }
  const vshort8 ones_s = {(short)0x3F80, (short)0x3F80, (short)0x3F80, (short)0x3F80,
                          (short)0x3F80, (short)0x3F80, (short)0x3F80, (short)0x3F80};
  const vbf16x8 onesf = __builtin_bit_cast(vbf16x8, ones_s);

  for (int kt = kt0; kt < kt1; ++kt) {
    const int k0 = kt * 64;

    // ---- QK^T from global K (L1/L2-resident; identical addrs across waves)
    vfloat4 st[2][4];
#pragma unroll
    for (int i = 0; i < 2; ++i)
#pragma unroll
      for (int j = 0; j < 4; ++j) { vfloat4 z = {0.f, 0.f, 0.f, 0.f}; st[i][j] = z; }
    __builtin_amdgcn_s_setprio(1);
#pragma unroll
    for (int j = 0; j < 4; ++j) {
      const unsigned short* kr = Kb + (size_t)(k0 + j * 16 + c16) * QKV_N;
      vbf16x8 kf0 = ld_frag(kr);
      vbf16x8 kf1 = ld_frag(kr + 32);
      vbf16x8 kf2 = ld_frag(kr + 64);
      vbf16x8 kf3 = ld_frag(kr + 96);
      st[0][j] = mfma16(kf0, qf[0][0], st[0][j]);
      st[1][j] = mfma16(kf0, qf[1][0], st[1][j]);
      st[0][j] = mfma16(kf1, qf[0][1], st[0][j]);
      st[1][j] = mfma16(kf1, qf[1][1], st[1][j]);
      st[0][j] = mfma16(kf2, qf[0][2], st[0][j]);
      st[1][j] = mfma16(kf2, qf[1][2], st[1][j]);
      st[0][j] = mfma16(kf3, qf[0][3], st[0][j]);
      st[1][j] = mfma16(kf3, qf[1][3], st[1][j]);
    }
    __builtin_amdgcn_s_setprio(0);

    // ---- softmax (exp2-domain, branch-free)
#pragma unroll
    for (int i = 0; i < 2; ++i) {
      const int qcol = q0 + w * 32 + i * 16 + c16;
      float mx = -1e30f;
#pragma unroll
      for (int j = 0; j < 4; ++j)
#pragma unroll
        for (int r = 0; r < 4; ++r) {
          int key = k0 + j * 16 + q4 * 4 + r;
          float v = st[i][j][r] * SM_LOG2E;
          v = (key > qcol) ? -1e30f : v;
          st[i][j][r] = v;
          mx = fmaxf(mx, v);
        }
      mx = fmaxf(mx, __shfl_xor(mx, 16));
      mx = fmaxf(mx, __shfl_xor(mx, 32));
      float mold = m_run[i];
      float mn = fmaxf(mold, mx);
      float a = __builtin_amdgcn_exp2f(mold - mn);
      m_run[i] = mn;
#pragma unroll
      for (int j = 0; j < 8; ++j)
#pragma unroll
        for (int r = 0; r < 4; ++r)
          of[i][j][r] *= a;
#pragma unroll
      for (int r = 0; r < 4; ++r) ofl[i][r] *= a;
#pragma unroll
      for (int j = 0; j < 4; ++j)
#pragma unroll
        for (int r = 0; r < 4; ++r)
          st[i][j][r] = __builtin_amdgcn_exp2f(st[i][j][r] - mn);
    }

    // ---- P -> per-wave LDS (no barrier; same wave reads back)
#pragma unroll
    for (int i = 0; i < 2; ++i)
#pragma unroll
      for (int j = 0; j < 4; ++j)
        *(vshort4*)(pw + (i * 16 + c16) * 72 + j * 16 + q4 * 4) =
            pack4f(st[i][j][0], st[i][j][1], st[i][j][2], st[i][j][3]);

    // ---- PV from global V^T (vf batched 4-wide to bound VGPR)
#pragma unroll
    for (int kk = 0; kk < 2; ++kk) {
      const unsigned short* vr = Vb + k0 + kk * 32;
      vbf16x8 p0 = ld_frag(pw + (c16) * 72 + kk * 32 + q4 * 8);
      vbf16x8 p1 = ld_frag(pw + (16 + c16) * 72 + kk * 32 + q4 * 8);
#pragma unroll
      for (int jh = 0; jh < 2; ++jh) {
        vbf16x8 vf0 = ld_frag(vr + (size_t)(jh * 64 +  0) * SEQ);
        vbf16x8 vf1 = ld_frag(vr + (size_t)(jh * 64 + 16) * SEQ);
        vbf16x8 vf2 = ld_frag(vr + (size_t)(jh * 64 + 32) * SEQ);
        vbf16x8 vf3 = ld_frag(vr + (size_t)(jh * 64 + 48) * SEQ);
        __builtin_amdgcn_s_setprio(1);
        of[0][jh * 4 + 0] = mfma16(vf0, p0, of[0][jh * 4 + 0]);
        of[1][jh * 4 + 0] = mfma16(vf0, p1, of[1][jh * 4 + 0]);
        of[0][jh * 4 + 1] = mfma16(vf1, p0, of[0][jh * 4 + 1]);
        of[1][jh * 4 + 1] = mfma16(vf1, p1, of[1][jh * 4 + 1]);
        of[0][jh * 4 + 2] = mfma16(vf2, p0, of[0][jh * 4 + 2]);
        of[1][jh * 4 + 2] = mfma16(vf2, p1, of[1][jh * 4 + 2]);
        of[0][jh * 4 + 3] = mfma16(vf3, p0, of[0][jh * 4 + 3]);
        of[1][jh * 4 + 3] = mfma16(vf3, p1, of[1][jh * 4 + 3]);
        __builtin_amdgcn_s_setprio(0);
      }
      ofl[0] = mfma16(onesf, p0, ofl[0]);
      ofl[1] = mfma16(onesf, p1, ofl[1]);
    }
  }

#pragma unroll
  for (int i = 0; i < 2; ++i) {
    int lr = w * 32 + i * 16 + c16;
    int qrow = q0 + lr;
    float l = ofl[i][0];
    if (chunk < 0) {
      float inv_l = 1.f / l;
#pragma unroll
      for (int jd = 0; jd < 8; ++jd)
        *(vshort4*)(attnb + (size_t)qrow * QSZ + h * HD + jd * 16 + q4 * 4) =
            pack4f(of[i][jd][0] * inv_l, of[i][jd][1] * inv_l,
                   of[i][jd][2] * inv_l, of[i][jd][3] * inv_l);
    } else if (chunk == 0) {
#pragma unroll
      for (int jd = 0; jd < 8; ++jd)
        *(vshort4*)(attnb + (size_t)qrow * QSZ + h * HD + jd * 16 + q4 * 4) =
            pack4f(of[i][jd][0], of[i][jd][1], of[i][jd][2], of[i][jd][3]);
      if (q4 == 0) { ml[t * 512 + lr * 4 + 0] = m_run[i]; ml[t * 512 + lr * 4 + 1] = l; }
    } else {
#pragma unroll
      for (int jd = 0; jd < 8; ++jd)
        *(vshort4*)(part1 + (size_t)t * 16384 + lr * 128 + jd * 16 + q4 * 4) =
            pack4f(of[i][jd][0], of[i][jd][1], of[i][jd][2], of[i][jd][3]);
      if (q4 == 0) { ml[t * 512 + lr * 4 + 2] = m_run[i]; ml[t * 512 + lr * 4 + 3] = l; }
    }
  }
}

// ---------------------------------------------------------------------------
// Fallback-path attention (R14 LDS-staged version, verified) -- used when the
// workspace is too small for the Vt buffer.
// ---------------------------------------------------------------------------
__global__ __launch_bounds__(256, 2) void attn_kernel_lds(
    const unsigned short* __restrict__ qkv,
    unsigned short* __restrict__ attnb,
    unsigned short* __restrict__ part1,
    float* __restrict__ ml)
{
  __shared__ __align__(16) unsigned short kvK[64 * 128];   // [kv][d] swizzled
  __shared__ __align__(16) unsigned short kvV[128 * 72];
  __shared__ __align__(16) unsigned short pb[4 * 32 * 72];
  const int tid = threadIdx.x, w = tid >> 6, lane = tid & 63;
  const int c16 = lane & 15, q4 = lane >> 4;

  int bid = blockIdx.x;
  int h, qt, chunk, kt0, kt1, t = 0;
  if (bid < 448) {
    h = bid >> 4; int s = bid & 15;
    qt = 15 - (s >> 1); chunk = s & 1;
    int half = qt + 1;
    kt0 = chunk * half; kt1 = kt0 + half;
    t = h * 8 + (qt - 8);
  } else {
    int d = bid - 448; h = d >> 3; qt = 7 - (d & 7); chunk = -1;
    kt0 = 0; kt1 = 2 * (qt + 1);
  }
  const int q0 = qt * 128;
  const int kvh = h / 7;
  unsigned short* pw = pb + w * 2304;

  vbf16x8 qf[2][4];
#pragma unroll
  for (int i = 0; i < 2; ++i)
#pragma unroll
    for (int kk = 0; kk < 4; ++kk)
      qf[i][kk] = ld_frag(qkv + (size_t)(q0 + w * 32 + i * 16 + c16) * QKV_N
                          + h * HD + kk * 32 + q4 * 8);

  vfloat4 of[2][8];
  vfloat4 ofl[2];
  float m_run[2];
#pragma unroll
  for (int i = 0; i < 2; ++i) {
    m_run[i] = -1e30f;
    vfloat4 z = {0.f, 0.f, 0.f, 0.f};
    ofl[i] = z;
#pragma unroll
    for (int j = 0; j < 8; ++j) of[i][j] = z;
  }
  const vshort8 ones_s = {(short)0x3F80, (short)0x3F80, (short)0x3F80, (short)0x3F80,
                          (short)0x3F80, (short)0x3F80, (short)0x3F80, (short)0x3F80};
  const vbf16x8 onesf = __builtin_bit_cast(vbf16x8, ones_s);

  vshort8 kreg[4], vreg[4];
#pragma unroll
  for (int it = 0; it < 4; ++it) {
    int ch = it * 256 + tid;
    kreg[it] = *(const vshort8*)(qkv + (size_t)(kt0 * 64 + (ch >> 4)) * QKV_N
                                 + QSZ + kvh * HD + (ch & 15) * 8);
    vreg[it] = *(const vshort8*)(qkv + (size_t)(kt0 * 64 + lane) * QKV_N
                                 + QSZ + 512 + kvh * HD + (it * 4 + w) * 8);
  }

  for (int kt = kt0; kt < kt1; ++kt) {
    const int k0 = kt * 64;
    __syncthreads();
#pragma unroll
    for (int it = 0; it < 4; ++it) {
      int ch = it * 256 + tid;
      int row = ch >> 4;
      *(vshort8*)(kvK + row * 128 + (((ch & 15) ^ (row & 7)) << 3)) = kreg[it];
    }
#pragma unroll
    for (int it = 0; it < 4; ++it) {
      int sub = it * 4 + w;
#pragma unroll
      for (int jj = 0; jj < 8; ++jj)
        kvV[(sub * 8 + jj) * 72 + lane] = (unsigned short)vreg[it][jj];
    }
    __syncthreads();
    if (kt + 1 < kt1) {
#pragma unroll
      for (int it = 0; it < 4; ++it) {
        int ch = it * 256 + tid;
        kreg[it] = *(const vshort8*)(qkv + (size_t)((kt + 1) * 64 + (ch >> 4)) * QKV_N
                                     + QSZ + kvh * HD + (ch & 15) * 8);
        vreg[it] = *(const vshort8*)(qkv + (size_t)((kt + 1) * 64 + lane) * QKV_N
                                     + QSZ + 512 + kvh * HD + (it * 4 + w) * 8);
      }
    }

    vfloat4 st[2][4];
#pragma unroll
    for (int i = 0; i < 2; ++i)
#pragma unroll
      for (int j = 0; j < 4; ++j) { vfloat4 z = {0.f, 0.f, 0.f, 0.f}; st[i][j] = z; }
    __builtin_amdgcn_s_setprio(1);
#pragma unroll
    for (int j = 0; j < 4; ++j)
#pragma unroll
      for (int kk = 0; kk < 4; ++kk) {
        vbf16x8 kf = ld_frag(kvK + (j * 16 + c16) * 128
                             + (((kk * 4 + q4) ^ (c16 & 7)) << 3));
        st[0][j] = mfma16(kf, qf[0][kk], st[0][j]);
        st[1][j] = mfma16(kf, qf[1][kk], st[1][j]);
      }
    __builtin_amdgcn_s_setprio(0);

#pragma unroll
    for (int i = 0; i < 2; ++i) {
      const int qcol = q0 + w * 32 + i * 16 + c16;
      float mx = -1e30f;
#pragma unroll
      for (int j = 0; j < 4; ++j)
#pragma unroll
        for (int r = 0; r < 4; ++r) {
          int key = k0 + j * 16 + q4 * 4 + r;
          float v = st[i][j][r] * SM_LOG2E;
          v = (key > qcol) ? -1e30f : v;
          st[i][j][r] = v;
          mx = fmaxf(mx, v);
        }
      mx = fmaxf(mx, __shfl_xor(mx, 16));
      mx = fmaxf(mx, __shfl_xor(mx, 32));
      float mold = m_run[i];
      float mn = fmaxf(mold, mx);
      float a = __builtin_amdgcn_exp2f(mold - mn);
      m_run[i] = mn;
#pragma unroll
      for (int j = 0; j < 8; ++j)
#pragma unroll
        for (int r = 0; r < 4; ++r)
          of[i][j][r] *= a;
#pragma unroll
      for (int r = 0; r < 4; ++r) ofl[i][r] *= a;
#pragma unroll
      for (int j = 0; j < 4; ++j)
#pragma unroll
        for (int r = 0; r < 4; ++r)
          st[i][j][r] = __builtin_amdgcn_exp2f(st[i][j][r] - mn);
    }

#pragma unroll
    for (int i = 0; i < 2; ++i)
#pragma unroll
      for (int j = 0; j < 4; ++j)
        *(vshort4*)(pw + (i * 16 + c16) * 72 + j * 16 + q4 * 4) =
            pack4f(st[i][j][0], st[i][j][1], st[i][j][2], st[i][j][3]);

    __builtin_amdgcn_s_setprio(1);
#pragma unroll
    for (int kk = 0; kk < 2; ++kk) {
      vbf16x8 p0 = ld_frag(pw + (c16) * 72 + kk * 32 + q4 * 8);
      vbf16x8 p1 = ld_frag(pw + (16 + c16) * 72 + kk * 32 + q4 * 8);
#pragma unroll
      for (int jd = 0; jd < 8; ++jd) {
        vbf16x8 vf = ld_frag(kvV + (jd * 16 + c16) * 72 + kk * 32 + q4 * 8);
        of[0][jd] = mfma16(vf, p0, of[0][jd]);
        of[1][jd] = mfma16(vf, p1, of[1][jd]);
      }
      ofl[0] = mfma16(onesf, p0, ofl[0]);
      ofl[1] = mfma16(onesf, p1, ofl[1]);
    }
    __builtin_amdgcn_s_setprio(0);
  }

#pragma unroll
  for (int i = 0; i < 2; ++i) {
    int lr = w * 32 + i * 16 + c16;
    int qrow = q0 + lr;
    float l = ofl[i][0];
    if (chunk < 0) {
      float inv_l = 1.f / l;
#pragma unroll
      for (int jd = 0; jd < 8; ++jd)
        *(vshort4*)(attnb + (size_t)qrow * QSZ + h * HD + jd * 16 + q4 * 4) =
            pack4f(of[i][jd][0] * inv_l, of[i][jd][1] * inv_l,
                   of[i][jd][2] * inv_l, of[i][jd][3] * inv_l);
    } else if (chunk == 0) {
#pragma unroll
      for (int jd = 0; jd < 8; ++jd)
        *(vshort4*)(attnb + (size_t)qrow * QSZ + h * HD + jd * 16 + q4 * 4) =
            pack4f(of[i][jd][0], of[i][jd][1], of[i][jd][2], of[i][jd][3]);
      if (q4 == 0) { ml[t * 512 + lr * 4 + 0] = m_run[i]; ml[t * 512 + lr * 4 + 1] = l; }
    } else {
#pragma unroll
      for (int jd = 0; jd < 8; ++jd)
        *(vshort4*)(part1 + (size_t)t * 16384 + lr * 128 + jd * 16 + q4 * 4) =
            pack4f(of[i][jd][0], of[i][jd][1], of[i][jd][2], of[i][jd][3]);
      if (q4 == 0) { ml[t * 512 + lr * 4 + 2] = m_run[i]; ml[t * 512 + lr * 4 + 3] = l; }
    }
  }
}

// ---------------------------------------------------------------------------
// NOTE: ml stores running max in exp2 (log2) domain -> combine uses exp2.
// ---------------------------------------------------------------------------
__global__ __launch_bounds__(256) void combine_kernel(
    unsigned short* __restrict__ attnb, const unsigned short* __restrict__ part1,
    const float* __restrict__ ml)
{
  int t = blockIdx.x;
  int h = t >> 3, qt = (t & 7) + 8;
  int lr = threadIdx.x >> 1, ch = (threadIdx.x & 1) * 64;
  int row = qt * 128 + lr;
  float m0 = ml[t * 512 + lr * 4 + 0], l0 = ml[t * 512 + lr * 4 + 1];
  float m1 = ml[t * 512 + lr * 4 + 2], l1 = ml[t * 512 + lr * 4 + 3];
  float M = fmaxf(m0, m1);
  float w0 = __builtin_amdgcn_exp2f(m0 - M), w1 = __builtin_amdgcn_exp2f(m1 - M);
  float inv = 1.f / (l0 * w0 + l1 * w1);
  unsigned short* dst = attnb + (size_t)row * QSZ + h * HD + ch;
  const unsigned short* src = part1 + (size_t)t * 16384 + lr * 128 + ch;
#pragma unroll
  for (int k = 0; k < 8; ++k) {
    vshort8 a = *(const vshort8*)(dst + k * 8);
    vshort8 b = *(const vshort8*)(src + k * 8);
    vshort8 o;
#pragma unroll
    for (int jj = 0; jj < 8; ++jj)
      o[jj] = (short)f2bf((bf2f((unsigned short)a[jj]) * w0 +
                           bf2f((unsigned short)b[jj]) * w1) * inv);
    *(vshort8*)(dst + k * 8) = o;
  }
}

// ---------------------------------------------------------------------------
extern "C" void kernel_launch(void* const* d_in, const int* in_sizes, int n_in,
                              void* d_out, int out_size, void* d_ws, size_t ws_size,
                              hipStream_t stream)
{
  const void* hidden = d_in[0];
  const int*  pos    = (const int*)d_in[1];
  const int*  qkv_qw = (const int*)d_in[2];
  const int*  qkv_qz = (const int*)d_in[3];
  const void* qkv_sc = d_in[4];
  const void* qkv_bs = d_in[5];
  const int*  o_qw   = (const int*)d_in[6];
  const int*  o_qz   = (const int*)d_in[7];
  const void* o_sc   = d_in[8];

  char* ws = (char*)d_ws;
  unsigned short* hidbf = (unsigned short*)d_out;  // dead once gemm1 done

  if (ws_size >= 67052560ULL) {
    // ------- big layout: single-launch GEMMs -------
    unsigned short* qkvb   = (unsigned short*)ws;               // [2048][4608]
    unsigned short* attnb  = (unsigned short*)(ws + 18874368);  // [2048][3584]
    unsigned short* W      = (unsigned short*)(ws + 33554432);  // weights 33 MB
    unsigned short* part1  = W;                                  // after gemm1
    float*          mlbuf  = (float*)(ws + 33554432 + 7340032);
    float2*         tbl    = (float2*)(ws + 41943040);           // 1 MB, rope only
    unsigned short* VtBuf  = (unsigned short*)(ws + 44040192);   // 2 MB, attn only
    unsigned short* scbf1  = (unsigned short*)(ws + 66584576);
    unsigned short* scbf2  = (unsigned short*)(ws + 66842624);
    unsigned short* biasbf = (unsigned short*)(ws + 67043328);
    int*            flag   = (int*)(ws + 67052544);

    detect_dtype<<<1, 256, 0, stream>>>((const unsigned short*)hidden, flag);
    convert_bf8<<<3584, 256, 0, stream>>>(hidden, hidbf, flag);
    convert_bf8<<<63, 256, 0, stream>>>(qkv_sc, scbf1, flag);
    convert_bf<<<18, 256, 0, stream>>>(qkv_bs, biasbf, flag);
    convert_bf8<<<49, 256, 0, stream>>>(o_sc, scbf2, flag);

    dequant_awq<<<2016, 256, 0, stream>>>(qkv_qw, qkv_qz, scbf1, W, 3584, 576, 576, 4608);
    gemm8p<192><<<dim3(24, 8), 512, 0, stream>>>(hidbf, W, biasbf, qkvb, 0, 4608, 3584, nullptr);
    vt_kernel<<<dim3(32, 8), 256, 0, stream>>>(qkvb, VtBuf);
    rope_table<<<512, 256, 0, stream>>>(pos, tbl);
    rope_apply<<<4096, 256, 0, stream>>>(qkvb, tbl);
    attn_kernel<<<672, 256, 0, stream>>>(qkvb, VtBuf, attnb, part1, mlbuf);
    combine_kernel<<<224, 256, 0, stream>>>(attnb, part1, mlbuf);
    dequant_awq<<<1568, 256, 0, stream>>>(o_qw, o_qz, scbf2, W, 3584, 448, 448, 3584);
    gemm8p<128><<<dim3(28, 8), 512, 0, stream>>>(attnb, W, nullptr, d_out, 0, 3584, 3584, flag);
  } else {
    // ------- chunked fallback (known-safe 43.7 MB) -------
    unsigned short* qkvb   = (unsigned short*)ws;               // [2048][4608]
    unsigned short* attnb  = (unsigned short*)(ws + 18874368);  // [2048][3584]
    unsigned short* wscr1  = attnb;                             // [2304][3584]
    float2*         tbl    = (float2*)(ws + 18874368);          // rope only
    unsigned short* part1  = (unsigned short*)(ws + 35389440);  // [224][16384]
    float*          mlbuf  = (float*)(ws + 42729472);           // [224][512]
    int*            flag   = (int*)(ws + 43188224);
    unsigned short* scbf1  = (unsigned short*)(ws + 43188240);
    unsigned short* scbf2  = (unsigned short*)(ws + 43446288);
    unsigned short* biasbf = (unsigned short*)(ws + 43646992);
    unsigned short* wscr2  = qkvb;

    detect_dtype<<<1, 256, 0, stream>>>((const unsigned short*)hidden, flag);
    convert_bf8<<<3584, 256, 0, stream>>>(hidden, hidbf, flag);
    convert_bf8<<<63, 256, 0, stream>>>(qkv_sc, scbf1, flag);
    convert_bf<<<18, 256, 0, stream>>>(qkv_bs, biasbf, flag);
    convert_bf8<<<49, 256, 0, stream>>>(o_sc, scbf2, flag);

    for (int c = 0; c < 2; ++c) {
      dequant_awq<<<1008, 256, 0, stream>>>(
          qkv_qw + c * 288, qkv_qz + c * 288, scbf1 + c * 2304, wscr1,
          3584, 288, 576, 4608);
      gemm8p<192><<<dim3(12, 8), 512, 0, stream>>>(
          hidbf, wscr1, biasbf + c * 2304, qkvb, c * 2304, 4608, 3584, nullptr);
    }
    rope_table<<<512, 256, 0, stream>>>(pos, tbl);
    rope_apply<<<4096, 256, 0, stream>>>(qkvb, tbl);
    attn_kernel_lds<<<672, 256, 0, stream>>>(qkvb, attnb, part1, mlbuf);
    combine_kernel<<<224, 256, 0, stream>>>(attnb, part1, mlbuf);
    for (int c = 0; c < 2; ++c) {
      dequant_awq<<<784, 256, 0, stream>>>(
          o_qw + c * 224, o_qz + c * 224, scbf2 + c * 1792, wscr2,
          3584, 224, 448, 3584);
      gemm8p<128><<<dim3(14, 8), 512, 0, stream>>>(
          attnb, wscr2, nullptr, d_out, c * 1792, 3584, 3584, flag);
    }
  }
}

// Round 9
// 368.794 us; speedup vs baseline: 1.4093x; 1.4093x over previous
//
#include <hip/hip_runtime.h>
#include <stdint.h>

// ---------------------------------------------------------------------------
// Qwen2-7B attention block on gfx950.
// R16: R14 attn + global V-transpose sourcing (DS-op diet).
//   R15 post-mortem: de-staging K/V = demand-fetch latency disaster (239us);
//   reg-prefetch + LDS staging is load-bearing. REVERTED to R14 structure.
//   New accounting: per-tile ~80 DS ops/thread, ~40% of the 7.9k-cyc/tile CU
//   budget on the shared LDS pipe; the 32x ds_write_b16 V-scatter is 40% of
//   DS ops. Fix: vt_kernel (verified in R15) materializes Vt[d][kv] in global;
//   attn's vreg prefetch loads Vt rows (coalesced) and fills kvV (pad-72,
//   read-side unchanged) with 4x ds_write_b128. DS ops 80 -> 52/thread/tile.
// GEMMs (BN=192/128 8-phase), RoPE, dequant unchanged.
// ---------------------------------------------------------------------------

typedef short vshort4 __attribute__((ext_vector_type(4)));
typedef short vshort8 __attribute__((ext_vector_type(8)));
typedef __bf16 vbf16x4 __attribute__((ext_vector_type(4)));
typedef __bf16 vbf16x8 __attribute__((ext_vector_type(8)));
typedef float vfloat4 __attribute__((ext_vector_type(4)));

#define SEQ 2048
#define NH 28
#define KVH 4
#define HD 128
#define QSZ 3584
#define QKV_N 4608
#define SM_SCALE 0.08838834764831845f
#define SM_LOG2E 0.1275174331f   /* SM_SCALE * log2(e) */

__device__ __forceinline__ float bf2f(unsigned short h) {
  union { unsigned int u; float f; } x; x.u = ((unsigned int)h) << 16; return x.f;
}
__device__ __forceinline__ unsigned short f2bf(float f) {
  union { unsigned int u; float f; } x; x.f = f;
  x.u += 0x7fff + ((x.u >> 16) & 1);
  return (unsigned short)(x.u >> 16);
}
__device__ __forceinline__ vbf16x8 ld_frag(const unsigned short* p) {
  return __builtin_bit_cast(vbf16x8, *(const vshort8*)p);
}
__device__ __forceinline__ vfloat4 mfma16(vbf16x8 a, vbf16x8 b, vfloat4 c) {
  return __builtin_amdgcn_mfma_f32_16x16x32_bf16(a, b, c, 0, 0, 0);
}
__device__ __forceinline__ void async_cp16(const unsigned short* g, unsigned short* l) {
  __builtin_amdgcn_global_load_lds((const __attribute__((address_space(1))) void*)g,
                                   (__attribute__((address_space(3))) void*)l, 16, 0, 0);
}
__device__ __forceinline__ vshort4 pack4f(float a, float b, float c, float d) {
  vbf16x4 t; t[0] = (__bf16)a; t[1] = (__bf16)b; t[2] = (__bf16)c; t[3] = (__bf16)d;
  return __builtin_bit_cast(vshort4, t);
}

// ---------------------------------------------------------------------------
__global__ __launch_bounds__(256) void detect_dtype(
    const unsigned short* __restrict__ h, int* __restrict__ flag)
{
  __shared__ int red[256];
  int cnt = 0;
#pragma unroll
  for (int i = 0; i < 8; ++i) {
    unsigned short u = h[threadIdx.x * 8 + i];
    int e = (u >> 7) & 0xFF;
    cnt += (e >= 100 && e <= 150) ? 1 : 0;
  }
  red[threadIdx.x] = cnt;
  __syncthreads();
  for (int s = 128; s > 0; s >>= 1) {
    if (threadIdx.x < s) red[threadIdx.x] += red[threadIdx.x + s];
    __syncthreads();
  }
  if (threadIdx.x == 0) flag[0] = (red[0] >= 1700) ? 1 : 0;
}

__global__ __launch_bounds__(256) void convert_bf(
    const void* __restrict__ src, unsigned short* __restrict__ dst,
    const int* __restrict__ flag)
{
  int i = blockIdx.x * 256 + threadIdx.x;
  if (flag[0]) dst[i] = ((const unsigned short*)src)[i];
  else         dst[i] = f2bf(((const float*)src)[i]);
}

__global__ __launch_bounds__(256) void convert_bf8(
    const void* __restrict__ src, unsigned short* __restrict__ dst,
    const int* __restrict__ flag)
{
  int i = (blockIdx.x * 256 + threadIdx.x) * 8;
  if (flag[0]) {
    *(vshort8*)(dst + i) = *(const vshort8*)((const unsigned short*)src + i);
  } else {
    const float* s = (const float*)src + i;
    float4 a = *(const float4*)s;
    float4 b = *(const float4*)(s + 4);
    vshort8 o;
    o[0] = (short)f2bf(a.x); o[1] = (short)f2bf(a.y);
    o[2] = (short)f2bf(a.z); o[3] = (short)f2bf(a.w);
    o[4] = (short)f2bf(b.x); o[5] = (short)f2bf(b.y);
    o[6] = (short)f2bf(b.z); o[7] = (short)f2bf(b.w);
    *(vshort8*)(dst + i) = o;
  }
}

// ---------------------------------------------------------------------------
__global__ __launch_bounds__(256) void dequant_awq(
    const int* __restrict__ qw, const int* __restrict__ qz,
    const unsigned short* __restrict__ scales,
    unsigned short* __restrict__ Wt,
    int Kdim, int CwChunk, int CwStride, int NoutStride)
{
  int idx = blockIdx.x * 256 + threadIdx.x;   // total = (Kdim/4)*CwChunk
  int kq = Kdim >> 2;
  int k4 = idx % kq;
  int c  = idx / kq;
  int k  = k4 * 4;
  int g  = k >> 7;
  int w0 = qw[(size_t)(k + 0) * CwStride + c];
  int w1 = qw[(size_t)(k + 1) * CwStride + c];
  int w2 = qw[(size_t)(k + 2) * CwStride + c];
  int w3 = qw[(size_t)(k + 3) * CwStride + c];
  int z  = qz[(size_t)g * CwStride + c];
#pragma unroll
  for (int j = 0; j < 8; ++j) {
    int sh = 4 * j;
    float zn = (float)((z >> sh) & 0xF);
    float s  = bf2f(scales[(size_t)g * NoutStride + c * 8 + j]);
    vshort4 o;
    o[0] = (short)f2bf(((float)((w0 >> sh) & 0xF) - zn) * s);
    o[1] = (short)f2bf(((float)((w1 >> sh) & 0xF) - zn) * s);
    o[2] = (short)f2bf(((float)((w2 >> sh) & 0xF) - zn) * s);
    o[3] = (short)f2bf(((float)((w3 >> sh) & 0xF) - zn) * s);
    *(vshort4*)(Wt + (size_t)(c * 8 + j) * Kdim + k) = o;
  }
}

// ---------------------------------------------------------------------------
// 8-phase 256-row GEMM.  C[m0..m0+256][n0..n0+BN] += A[256xK] * Bt[BNxK]^T.
// ---------------------------------------------------------------------------
#define BAR()   asm volatile("s_barrier" ::: "memory")
#define LGKM0() asm volatile("s_waitcnt lgkmcnt(0)" ::: "memory")

template<int BN>
__global__ __launch_bounds__(512, 2) void gemm8p(
    const unsigned short* __restrict__ A,
    const unsigned short* __restrict__ Bt,
    const unsigned short* __restrict__ bias,
    void* __restrict__ Cv, int n_base, int ldc, int K,
    const int* __restrict__ oflag)
{
  constexpr int HB  = (BN / 2) * 64;     // half of B region (B region = BN*64)
  constexpr int HA  = 128 * 64;          // A-half elems
  constexpr int GRP = 2 * HB + 2 * HA;   // one K-tile group
  constexpr int NC  = BN / 64;           // col frags per wave (4 / 3 / 2)
  constexpr int CH  = NC / 2;            // (not used by BN=192 path)
  __shared__ __align__(16) unsigned short lds[2 * GRP];

  const int tid = threadIdx.x;
  const int w = tid >> 6, lane = tid & 63;
  const int c16 = lane & 15, q4 = lane >> 4;
  const int wm = w >> 2, wn = w & 3;
  const int m0 = blockIdx.y * 256, n0 = blockIdx.x * BN;

  // staging: linear LDS dest, inverse-swizzled global source (16B slot ^ row&7)
  const int srow = tid >> 3;
  const int scol = ((tid & 7) ^ (srow & 7)) * 8;
  const unsigned short* const aS = A  + (size_t)(m0 + srow) * K + scol;
  const unsigned short* const bS = Bt + (size_t)(n0 + srow) * K + scol;
  const int wst = w * 512;               // wave slot within each 8KB sweep

  // swizzled ds_read offsets (elements)
  int offA[4][2], offB[NC][2];
  const int swz = c16 & 7;
#pragma unroll
  for (int kh = 0; kh < 2; ++kh) {
    const int ko = ((kh * 4 + q4) ^ swz) * 8;
#pragma unroll
    for (int i = 0; i < 4; ++i) offA[i][kh] = (i * 16 + c16) * 64 + ko;
#pragma unroll
    for (int cj = 0; cj < NC; ++cj)
      offB[cj][kh] = ((wn & 1) * (BN / 4) + cj * 16 + c16) * 64 + ko;
  }
  const int aB0 = 2 * HB + wm * HA;
  const int bB0 = (wn >> 1) * HB;

  vbf16x8 af[4][2], bfr[NC][2];
  vfloat4 acc[8][NC];
#pragma unroll
  for (int i = 0; i < 8; ++i)
#pragma unroll
    for (int c = 0; c < NC; ++c) { vfloat4 z = {0.f, 0.f, 0.f, 0.f}; acc[i][c] = z; }

#define LD_A(g_, rh_) do { \
    const unsigned short* p_ = lds + (g_) * GRP + aB0 + (rh_) * 4096; \
    _Pragma("unroll") for (int i_ = 0; i_ < 4; ++i_) { \
      af[i_][0] = ld_frag(p_ + offA[i_][0]); af[i_][1] = ld_frag(p_ + offA[i_][1]); } } while (0)
#define MMg(rb_, c0_, cn_) do { \
    __builtin_amdgcn_s_setprio(1); \
    _Pragma("unroll") for (int i_ = 0; i_ < 4; ++i_) \
    _Pragma("unroll") for (int c_ = 0; c_ < (cn_); ++c_) { \
      acc[(rb_) + i_][(c0_) + c_] = mfma16(af[i_][0], bfr[(c0_) + c_][0], acc[(rb_) + i_][(c0_) + c_]); \
      acc[(rb_) + i_][(c0_) + c_] = mfma16(af[i_][1], bfr[(c0_) + c_][1], acc[(rb_) + i_][(c0_) + c_]); } \
    __builtin_amdgcn_s_setprio(0); } while (0)

  const int nT  = K >> 6;
  const int nIt = nT >> 1;

  if constexpr (BN == 192) {
    // ---- sweep staging: 1 cp16/thread each; B=3 sweeps, A=4 sweeps ----
#define SWB(g_, s_, t_) async_cp16(bS + (size_t)(s_) * 64 * K + (size_t)(t_) * 64, \
                                   lds + (g_) * GRP + (s_) * 4096 + wst)
#define SWA(g_, s_, t_) async_cp16(aS + (size_t)(s_) * 64 * K + (size_t)(t_) * 64, \
                                   lds + (g_) * GRP + 2 * HB + (s_) * 4096 + wst)
#define LDB01(g_) do { const unsigned short* p_ = lds + (g_) * GRP + bB0; \
    bfr[0][0] = ld_frag(p_ + offB[0][0]); bfr[0][1] = ld_frag(p_ + offB[0][1]); \
    bfr[1][0] = ld_frag(p_ + offB[1][0]); bfr[1][1] = ld_frag(p_ + offB[1][1]); } while (0)
#define LDB2(g_) do { const unsigned short* p_ = lds + (g_) * GRP + bB0; \
    bfr[2][0] = ld_frag(p_ + offB[2][0]); bfr[2][1] = ld_frag(p_ + offB[2][1]); } while (0)
#define VM2() asm volatile("s_waitcnt vmcnt(2)" ::: "memory")

    // prologue: tile0 full (7 sweeps), tile1 B0,B1
    SWB(0, 0, 0); SWB(0, 1, 0); SWB(0, 2, 0);
    SWA(0, 0, 0); SWA(0, 1, 0); SWA(0, 2, 0); SWA(0, 3, 0);
    SWB(1, 0, 1); SWB(1, 1, 1);
    VM2(); BAR();

    for (int it = 0; it < nIt - 1; ++it) {
      const int tO = 2 * it + 1, tE2 = 2 * it + 2, tO2 = 2 * it + 3;
      // ph0: read grp0 A rows0-3 + B cols0-1; stage O tail
      LD_A(0, 0); LDB01(0);
      SWB(1, 2, tO); SWA(1, 0, tO);
      BAR(); LGKM0(); MMg(0, 0, 2); BAR();
      // ph1
      LDB2(0);
      SWA(1, 1, tO); SWA(1, 2, tO);
      BAR(); LGKM0(); MMg(0, 2, 1); BAR();
      // ph2
      LD_A(0, 1);
      SWA(1, 3, tO);
      BAR(); LGKM0(); MMg(4, 0, 2); BAR();
      // ph3: grp0 free after ph2 bar; start E2; drain O (only E2.B0/B1 newer)
      SWB(0, 0, tE2); SWB(0, 1, tE2);
      VM2(); BAR(); MMg(4, 2, 1); BAR();
      // ph4
      LD_A(1, 0); LDB01(1);
      SWB(0, 2, tE2); SWA(0, 0, tE2);
      BAR(); LGKM0(); MMg(0, 0, 2); BAR();
      // ph5
      LDB2(1);
      SWA(0, 1, tE2); SWA(0, 2, tE2);
      BAR(); LGKM0(); MMg(0, 2, 1); BAR();
      // ph6
      LD_A(1, 1);
      SWA(0, 3, tE2);
      BAR(); LGKM0(); MMg(4, 0, 2); BAR();
      // ph7: start O2; drain E2 (only O2.B0/B1 newer)
      SWB(1, 0, tO2); SWB(1, 1, tO2);
      VM2(); BAR(); MMg(4, 2, 1); BAR();
    }

    // peeled: grp0 = tile nT-2 (fully staged); grp1 = tile nT-1 (B0,B1 staged)
    {
      const int tO = nT - 1;
      LD_A(0, 0); LDB01(0);
      SWB(1, 2, tO); SWA(1, 0, tO);
      BAR(); LGKM0(); MMg(0, 0, 2); BAR();
      LDB2(0);
      SWA(1, 1, tO); SWA(1, 2, tO);
      BAR(); LGKM0(); MMg(0, 2, 1); BAR();
      LD_A(0, 1);
      SWA(1, 3, tO);
      BAR(); LGKM0(); MMg(4, 0, 2); BAR();
      asm volatile("s_waitcnt vmcnt(0)" ::: "memory");
      BAR(); MMg(4, 2, 1);
      LD_A(1, 0); LDB01(1); LDB2(1);
      LGKM0(); MMg(0, 0, 2); MMg(0, 2, 1);
      LD_A(1, 1);
      LGKM0(); MMg(4, 0, 2); MMg(4, 2, 1);
    }
#undef SWB
#undef SWA
#undef LDB01
#undef LDB2
#undef VM2
  } else {
    // ---- BN=256 / BN=128 path (verified in R8, unchanged) ----
#define STG_A(g_, h_, t_) do { \
    const unsigned short* s_ = aS + (size_t)(h_) * 128 * K + (size_t)(t_) * 64; \
    unsigned short* d_ = lds + (g_) * GRP + 2 * HB + (h_) * HA + wst; \
    async_cp16(s_, d_); async_cp16(s_ + (size_t)64 * K, d_ + 4096); } while (0)
#define STG_B(g_, h_, t_) do { \
    const unsigned short* s_ = bS + (size_t)(h_) * (BN / 2) * K + (size_t)(t_) * 64; \
    unsigned short* d_ = lds + (g_) * GRP + (h_) * HB + wst; \
    async_cp16(s_, d_); \
    if constexpr (BN == 256) async_cp16(s_ + (size_t)64 * K, d_ + 4096); } while (0)
#define VMW() do { if constexpr (BN == 256) asm volatile("s_waitcnt vmcnt(6)" ::: "memory"); \
                   else                     asm volatile("s_waitcnt vmcnt(4)" ::: "memory"); } while (0)
#define LD_B(g_) do { \
    const unsigned short* p_ = lds + (g_) * GRP + bB0; \
    _Pragma("unroll") for (int c_ = 0; c_ < NC; ++c_) { \
      bfr[c_][0] = ld_frag(p_ + offB[c_][0]); bfr[c_][1] = ld_frag(p_ + offB[c_][1]); } } while (0)

    // prologue: tile0 full, tile1 B0,B1,A0
    STG_B(0, 0, 0); STG_B(0, 1, 0); STG_A(0, 0, 0); STG_A(0, 1, 0);
    STG_B(1, 0, 1); STG_B(1, 1, 1); STG_A(1, 0, 1);
    VMW(); BAR();

    for (int it = 0; it < nIt - 1; ++it) {
      const int tE = 2 * it + 2, tO = 2 * it + 3;
      // ph0
      LD_A(0, 0); LD_B(0);
      STG_A(1, 1, tO - 2);
      BAR(); LGKM0(); MMg(0, 0, CH); BAR();
      // ph1
      STG_B(0, 0, tE);
      BAR(); LGKM0(); MMg(0, CH, CH); BAR();
      // ph2
      LD_A(0, 1);
      STG_B(0, 1, tE);
      BAR(); LGKM0(); MMg(4, 0, CH); BAR();
      // ph3
      STG_A(0, 0, tE);
      VMW(); BAR(); LGKM0(); MMg(4, CH, CH); BAR();
      // ph4
      LD_A(1, 0); LD_B(1);
      STG_A(0, 1, tE);
      BAR(); LGKM0(); MMg(0, 0, CH); BAR();
      // ph5
      STG_B(1, 0, tO);
      BAR(); LGKM0(); MMg(0, CH, CH); BAR();
      // ph6
      LD_A(1, 1);
      STG_B(1, 1, tO);
      BAR(); LGKM0(); MMg(4, 0, CH); BAR();
      // ph7
      STG_A(1, 0, tO);
      VMW(); BAR(); LGKM0(); MMg(4, CH, CH); BAR();
    }

    // peeled last iteration
    LD_A(0, 0); LD_B(0);
    STG_A(1, 1, nT - 1);
    BAR(); LGKM0();
    MMg(0, 0, CH); MMg(0, CH, CH);
    LD_A(0, 1);
    LGKM0();
    MMg(4, 0, CH); MMg(4, CH, CH);
    asm volatile("s_waitcnt vmcnt(0)" ::: "memory");
    BAR();
    LD_A(1, 0); LD_B(1);
    MMg(0, 0, CH); MMg(0, CH, CH);
    LD_A(1, 1);
    LGKM0();
    MMg(4, 0, CH); MMg(4, CH, CH);
#undef STG_A
#undef STG_B
#undef VMW
#undef LD_B
  }

  // ---- epilogue ----
  const int bfm = (oflag == nullptr) ? 1 : oflag[0];
#pragma unroll
  for (int ri = 0; ri < 8; ++ri) {
    const int m = m0 + wm * 128 + ri * 16 + q4 * 4;
#pragma unroll
    for (int cj = 0; cj < NC; ++cj) {
      const int n = n0 + wn * (BN / 4) + cj * 16 + c16;
      const float bv = bias ? bf2f(bias[n]) : 0.f;
#pragma unroll
      for (int r = 0; r < 4; ++r) {
        const float v = acc[ri][cj][r] + bv;
        const size_t idx = (size_t)(m + r) * ldc + n + n_base;
        if (bfm) ((unsigned short*)Cv)[idx] = f2bf(v);
        else     ((float*)Cv)[idx] = v;
      }
    }
  }
#undef LD_A
#undef MMg
}

// ---------------------------------------------------------------------------
// RoPE: precompute sincos table [SEQ][64] (float2), then vectorized apply.
// ---------------------------------------------------------------------------
__global__ __launch_bounds__(256) void rope_table(
    const int* __restrict__ pos, float2* __restrict__ tbl)
{
  int idx = blockIdx.x * 256 + threadIdx.x;  // SEQ*64 = 131072
  int j = idx & 63, s = idx >> 6;
  float inv = exp2f(-(float)j * 0.31143079014569017f);  // 1e6^(-j/64)
  float ang = (float)pos[s] * inv;
  float sn, cs;
  sincosf(ang, &sn, &cs);
  tbl[idx] = make_float2(cs, sn);
}

__global__ __launch_bounds__(256) void rope_apply(
    unsigned short* __restrict__ qkv, const float2* __restrict__ tbl)
{
  int idx = blockIdx.x * 256 + threadIdx.x;  // SEQ*32*16 = 1048576
  int j4 = idx & 15;
  int h2 = (idx >> 4) & 31;
  int s = idx >> 9;
  int jb = j4 * 4;
  unsigned short* row = qkv + (size_t)s * QKV_N
                        + ((h2 < NH) ? h2 * HD : QSZ + (h2 - NH) * HD);
  vshort4 x1 = *(const vshort4*)(row + jb);
  vshort4 x2 = *(const vshort4*)(row + jb + 64);
  const float2* tp = tbl + s * 64 + jb;
  vshort4 o1, o2;
#pragma unroll
  for (int q = 0; q < 4; ++q) {
    float2 cn = tp[q];
    float a = bf2f((unsigned short)x1[q]);
    float b = bf2f((unsigned short)x2[q]);
    o1[q] = (short)f2bf(a * cn.x - b * cn.y);
    o2[q] = (short)f2bf(b * cn.x + a * cn.y);
  }
  *(vshort4*)(row + jb) = o1;
  *(vshort4*)(row + jb + 64) = o2;
}

// ---------------------------------------------------------------------------
// V transpose: Vt[kvh*128+d][kv] from qkvb V region (V needs no RoPE).
// grid (32, 8): 64(s) x 64(d) tiles. 2MB total.  [verified in R15]
// ---------------------------------------------------------------------------
__global__ __launch_bounds__(256) void vt_kernel(
    const unsigned short* __restrict__ qkv, unsigned short* __restrict__ Vt)
{
  __shared__ unsigned short tile[64][72];
  const int s0 = blockIdx.x * 64;
  const int dg = blockIdx.y * 64;          // global index into [0,512)
  const int kvh = dg >> 7, d0 = dg & 127;
  const int tid = threadIdx.x;
#pragma unroll
  for (int it = 0; it < 2; ++it) {
    int row = it * 32 + (tid >> 3);
    int dc = (tid & 7) * 8;
    *(vshort8*)&tile[row][dc] =
        *(const vshort8*)(qkv + (size_t)(s0 + row) * QKV_N + QSZ + 512
                          + kvh * HD + d0 + dc);
  }
  __syncthreads();
#pragma unroll
  for (int it = 0; it < 2; ++it) {
    int dr = it * 32 + (tid >> 3);
    int sc = (tid & 7) * 8;
    vshort8 o;
#pragma unroll
    for (int e = 0; e < 8; ++e) o[e] = (short)tile[sc + e][dr];
    *(vshort8*)(Vt + (size_t)(dg + dr) * SEQ + s0 + sc) = o;
  }
}

// ---------------------------------------------------------------------------
// GQA causal flash attention (R14 structure).
// R16: kvV filled from global Vt with 4x ds_write_b128 (was 32x b16 scatter);
//      kvV pad-72 read side unchanged. kvK swizzled [64][128]. 53248B LDS.
// ---------------------------------------------------------------------------
__global__ __launch_bounds__(256, 2) void attn_kernel(
    const unsigned short* __restrict__ qkv,
    const unsigned short* __restrict__ Vt,
    unsigned short* __restrict__ attnb,
    unsigned short* __restrict__ part1,
    float* __restrict__ ml)
{
  __shared__ __align__(16) unsigned short kvK[64 * 128];   // [kv][d] swizzled
  __shared__ __align__(16) unsigned short kvV[128 * 72];   // [d][kv] pad-72
  __shared__ __align__(16) unsigned short pb[4 * 32 * 72];
  const int tid = threadIdx.x, w = tid >> 6, lane = tid & 63;
  const int c16 = lane & 15, q4 = lane >> 4;

  int bid = blockIdx.x;
  int h, qt, chunk, kt0, kt1, t = 0;
  if (bid < 448) {
    h = bid >> 4; int s = bid & 15;
    qt = 15 - (s >> 1); chunk = s & 1;
    int half = qt + 1;
    kt0 = chunk * half; kt1 = kt0 + half;
    t = h * 8 + (qt - 8);
  } else {
    int d = bid - 448; h = d >> 3; qt = 7 - (d & 7); chunk = -1;
    kt0 = 0; kt1 = 2 * (qt + 1);
  }
  const int q0 = qt * 128;
  const int kvh = h / 7;
  unsigned short* pw = pb + w * 2304;

  // V staging source: Vt rows, coalesced (8 threads share a 128B segment)
  const int vd  = tid >> 3;            // d row 0..31 (+32 per it)
  const int vkc = (tid & 7) * 8;       // kv col within tile
  const unsigned short* const VtB = Vt + (size_t)(kvh * 128) * SEQ;

  vbf16x8 qf[2][4];
#pragma unroll
  for (int i = 0; i < 2; ++i)
#pragma unroll
    for (int kk = 0; kk < 4; ++kk)
      qf[i][kk] = ld_frag(qkv + (size_t)(q0 + w * 32 + i * 16 + c16) * QKV_N
                          + h * HD + kk * 32 + q4 * 8);

  vfloat4 of[2][8];
  vfloat4 ofl[2];
  float m_run[2];
#pragma unroll
  for (int i = 0; i < 2; ++i) {
    m_run[i] = -1e30f;
    vfloat4 z = {0.f, 0.f, 0.f, 0.f};
    ofl[i] = z;
#pragma unroll
    for (int j = 0; j < 8; ++j) of[i][j] = z;
  }
  const vshort8 ones_s = {(short)0x3F80, (short)0x3F80, (short)0x3F80, (short)0x3F80,
                          (short)0x3F80, (short)0x3F80, (short)0x3F80, (short)0x3F80};
  const vbf16x8 onesf = __builtin_bit_cast(vbf16x8, ones_s);

  vshort8 kreg[4], vreg[4];
#pragma unroll
  for (int it = 0; it < 4; ++it) {
    int ch = it * 256 + tid;
    kreg[it] = *(const vshort8*)(qkv + (size_t)(kt0 * 64 + (ch >> 4)) * QKV_N
                                 + QSZ + kvh * HD + (ch & 15) * 8);
    vreg[it] = *(const vshort8*)(VtB + (size_t)(it * 32 + vd) * SEQ
                                 + kt0 * 64 + vkc);
  }

  for (int kt = kt0; kt < kt1; ++kt) {
    const int k0 = kt * 64;
    __syncthreads();
#pragma unroll
    for (int it = 0; it < 4; ++it) {
      int ch = it * 256 + tid;
      int row = ch >> 4;
      *(vshort8*)(kvK + row * 128 + (((ch & 15) ^ (row & 7)) << 3)) = kreg[it];
    }
#pragma unroll
    for (int it = 0; it < 4; ++it)
      *(vshort8*)(kvV + (it * 32 + vd) * 72 + vkc) = vreg[it];
    __syncthreads();
    if (kt + 1 < kt1) {
#pragma unroll
      for (int it = 0; it < 4; ++it) {
        int ch = it * 256 + tid;
        kreg[it] = *(const vshort8*)(qkv + (size_t)((kt + 1) * 64 + (ch >> 4)) * QKV_N
                                     + QSZ + kvh * HD + (ch & 15) * 8);
        vreg[it] = *(const vshort8*)(VtB + (size_t)(it * 32 + vd) * SEQ
                                     + (kt + 1) * 64 + vkc);
      }
    }

    vfloat4 st[2][4];
#pragma unroll
    for (int i = 0; i < 2; ++i)
#pragma unroll
      for (int j = 0; j < 4; ++j) { vfloat4 z = {0.f, 0.f, 0.f, 0.f}; st[i][j] = z; }
    __builtin_amdgcn_s_setprio(1);
#pragma unroll
    for (int j = 0; j < 4; ++j)
#pragma unroll
      for (int kk = 0; kk < 4; ++kk) {
        vbf16x8 kf = ld_frag(kvK + (j * 16 + c16) * 128
                             + (((kk * 4 + q4) ^ (c16 & 7)) << 3));
        st[0][j] = mfma16(kf, qf[0][kk], st[0][j]);
        st[1][j] = mfma16(kf, qf[1][kk], st[1][j]);
      }
    __builtin_amdgcn_s_setprio(0);

#pragma unroll
    for (int i = 0; i < 2; ++i) {
      const int qcol = q0 + w * 32 + i * 16 + c16;
      float mx = -1e30f;
#pragma unroll
      for (int j = 0; j < 4; ++j)
#pragma unroll
        for (int r = 0; r < 4; ++r) {
          int key = k0 + j * 16 + q4 * 4 + r;
          float v = st[i][j][r] * SM_LOG2E;
          v = (key > qcol) ? -1e30f : v;
          st[i][j][r] = v;
          mx = fmaxf(mx, v);
        }
      mx = fmaxf(mx, __shfl_xor(mx, 16));
      mx = fmaxf(mx, __shfl_xor(mx, 32));
      float mold = m_run[i];
      float mn = fmaxf(mold, mx);
      float a = __builtin_amdgcn_exp2f(mold - mn);
      m_run[i] = mn;
#pragma unroll
      for (int j = 0; j < 8; ++j)
#pragma unroll
        for (int r = 0; r < 4; ++r)
          of[i][j][r] *= a;
#pragma unroll
      for (int r = 0; r < 4; ++r) ofl[i][r] *= a;
#pragma unroll
      for (int j = 0; j < 4; ++j)
#pragma unroll
        for (int r = 0; r < 4; ++r)
          st[i][j][r] = __builtin_amdgcn_exp2f(st[i][j][r] - mn);
    }

#pragma unroll
    for (int i = 0; i < 2; ++i)
#pragma unroll
      for (int j = 0; j < 4; ++j)
        *(vshort4*)(pw + (i * 16 + c16) * 72 + j * 16 + q4 * 4) =
            pack4f(st[i][j][0], st[i][j][1], st[i][j][2], st[i][j][3]);

    __builtin_amdgcn_s_setprio(1);
#pragma unroll
    for (int kk = 0; kk < 2; ++kk) {
      vbf16x8 p0 = ld_frag(pw + (c16) * 72 + kk * 32 + q4 * 8);
      vbf16x8 p1 = ld_frag(pw + (16 + c16) * 72 + kk * 32 + q4 * 8);
#pragma unroll
      for (int jd = 0; jd < 8; ++jd) {
        vbf16x8 vf = ld_frag(kvV + (jd * 16 + c16) * 72 + kk * 32 + q4 * 8);
        of[0][jd] = mfma16(vf, p0, of[0][jd]);
        of[1][jd] = mfma16(vf, p1, of[1][jd]);
      }
      ofl[0] = mfma16(onesf, p0, ofl[0]);
      ofl[1] = mfma16(onesf, p1, ofl[1]);
    }
    __builtin_amdgcn_s_setprio(0);
  }

#pragma unroll
  for (int i = 0; i < 2; ++i) {
    int lr = w * 32 + i * 16 + c16;
    int qrow = q0 + lr;
    float l = ofl[i][0];
    if (chunk < 0) {
      float inv_l = 1.f / l;
#pragma unroll
      for (int jd = 0; jd < 8; ++jd)
        *(vshort4*)(attnb + (size_t)qrow * QSZ + h * HD + jd * 16 + q4 * 4) =
            pack4f(of[i][jd][0] * inv_l, of[i][jd][1] * inv_l,
                   of[i][jd][2] * inv_l, of[i][jd][3] * inv_l);
    } else if (chunk == 0) {
#pragma unroll
      for (int jd = 0; jd < 8; ++jd)
        *(vshort4*)(attnb + (size_t)qrow * QSZ + h * HD + jd * 16 + q4 * 4) =
            pack4f(of[i][jd][0], of[i][jd][1], of[i][jd][2], of[i][jd][3]);
      if (q4 == 0) { ml[t * 512 + lr * 4 + 0] = m_run[i]; ml[t * 512 + lr * 4 + 1] = l; }
    } else {
#pragma unroll
      for (int jd = 0; jd < 8; ++jd)
        *(vshort4*)(part1 + (size_t)t * 16384 + lr * 128 + jd * 16 + q4 * 4) =
            pack4f(of[i][jd][0], of[i][jd][1], of[i][jd][2], of[i][jd][3]);
      if (q4 == 0) { ml[t * 512 + lr * 4 + 2] = m_run[i]; ml[t * 512 + lr * 4 + 3] = l; }
    }
  }
}

// ---------------------------------------------------------------------------
// Fallback-path attention (R14 version, verified) -- no Vt buffer available.
// ---------------------------------------------------------------------------
__global__ __launch_bounds__(256, 2) void attn_kernel_lds(
    const unsigned short* __restrict__ qkv,
    unsigned short* __restrict__ attnb,
    unsigned short* __restrict__ part1,
    float* __restrict__ ml)
{
  __shared__ __align__(16) unsigned short kvK[64 * 128];   // [kv][d] swizzled
  __shared__ __align__(16) unsigned short kvV[128 * 72];
  __shared__ __align__(16) unsigned short pb[4 * 32 * 72];
  const int tid = threadIdx.x, w = tid >> 6, lane = tid & 63;
  const int c16 = lane & 15, q4 = lane >> 4;

  int bid = blockIdx.x;
  int h, qt, chunk, kt0, kt1, t = 0;
  if (bid < 448) {
    h = bid >> 4; int s = bid & 15;
    qt = 15 - (s >> 1); chunk = s & 1;
    int half = qt + 1;
    kt0 = chunk * half; kt1 = kt0 + half;
    t = h * 8 + (qt - 8);
  } else {
    int d = bid - 448; h = d >> 3; qt = 7 - (d & 7); chunk = -1;
    kt0 = 0; kt1 = 2 * (qt + 1);
  }
  const int q0 = qt * 128;
  const int kvh = h / 7;
  unsigned short* pw = pb + w * 2304;

  vbf16x8 qf[2][4];
#pragma unroll
  for (int i = 0; i < 2; ++i)
#pragma unroll
    for (int kk = 0; kk < 4; ++kk)
      qf[i][kk] = ld_frag(qkv + (size_t)(q0 + w * 32 + i * 16 + c16) * QKV_N
                          + h * HD + kk * 32 + q4 * 8);

  vfloat4 of[2][8];
  vfloat4 ofl[2];
  float m_run[2];
#pragma unroll
  for (int i = 0; i < 2; ++i) {
    m_run[i] = -1e30f;
    vfloat4 z = {0.f, 0.f, 0.f, 0.f};
    ofl[i] = z;
#pragma unroll
    for (int j = 0; j < 8; ++j) of[i][j] = z;
  }
  const vshort8 ones_s = {(short)0x3F80, (short)0x3F80, (short)0x3F80, (short)0x3F80,
                          (short)0x3F80, (short)0x3F80, (short)0x3F80, (short)0x3F80};
  const vbf16x8 onesf = __builtin_bit_cast(vbf16x8, ones_s);

  vshort8 kreg[4], vreg[4];
#pragma unroll
  for (int it = 0; it < 4; ++it) {
    int ch = it * 256 + tid;
    kreg[it] = *(const vshort8*)(qkv + (size_t)(kt0 * 64 + (ch >> 4)) * QKV_N
                                 + QSZ + kvh * HD + (ch & 15) * 8);
    vreg[it] = *(const vshort8*)(qkv + (size_t)(kt0 * 64 + lane) * QKV_N
                                 + QSZ + 512 + kvh * HD + (it * 4 + w) * 8);
  }

  for (int kt = kt0; kt < kt1; ++kt) {
    const int k0 = kt * 64;
    __syncthreads();
#pragma unroll
    for (int it = 0; it < 4; ++it) {
      int ch = it * 256 + tid;
      int row = ch >> 4;
      *(vshort8*)(kvK + row * 128 + (((ch & 15) ^ (row & 7)) << 3)) = kreg[it];
    }
#pragma unroll
    for (int it = 0; it < 4; ++it) {
      int sub = it * 4 + w;
#pragma unroll
      for (int jj = 0; jj < 8; ++jj)
        kvV[(sub * 8 + jj) * 72 + lane] = (unsigned short)vreg[it][jj];
    }
    __syncthreads();
    if (kt + 1 < kt1) {
#pragma unroll
      for (int it = 0; it < 4; ++it) {
        int ch = it * 256 + tid;
        kreg[it] = *(const vshort8*)(qkv + (size_t)((kt + 1) * 64 + (ch >> 4)) * QKV_N
                                     + QSZ + kvh * HD + (ch & 15) * 8);
        vreg[it] = *(const vshort8*)(qkv + (size_t)((kt + 1) * 64 + lane) * QKV_N
                                     + QSZ + 512 + kvh * HD + (it * 4 + w) * 8);
      }
    }

    vfloat4 st[2][4];
#pragma unroll
    for (int i = 0; i < 2; ++i)
#pragma unroll
      for (int j = 0; j < 4; ++j) { vfloat4 z = {0.f, 0.f, 0.f, 0.f}; st[i][j] = z; }
    __builtin_amdgcn_s_setprio(1);
#pragma unroll
    for (int j = 0; j < 4; ++j)
#pragma unroll
      for (int kk = 0; kk < 4; ++kk) {
        vbf16x8 kf = ld_frag(kvK + (j * 16 + c16) * 128
                             + (((kk * 4 + q4) ^ (c16 & 7)) << 3));
        st[0][j] = mfma16(kf, qf[0][kk], st[0][j]);
        st[1][j] = mfma16(kf, qf[1][kk], st[1][j]);
      }
    __builtin_amdgcn_s_setprio(0);

#pragma unroll
    for (int i = 0; i < 2; ++i) {
      const int qcol = q0 + w * 32 + i * 16 + c16;
      float mx = -1e30f;
#pragma unroll
      for (int j = 0; j < 4; ++j)
#pragma unroll
        for (int r = 0; r < 4; ++r) {
          int key = k0 + j * 16 + q4 * 4 + r;
          float v = st[i][j][r] * SM_LOG2E;
          v = (key > qcol) ? -1e30f : v;
          st[i][j][r] = v;
          mx = fmaxf(mx, v);
        }
      mx = fmaxf(mx, __shfl_xor(mx, 16));
      mx = fmaxf(mx, __shfl_xor(mx, 32));
      float mold = m_run[i];
      float mn = fmaxf(mold, mx);
      float a = __builtin_amdgcn_exp2f(mold - mn);
      m_run[i] = mn;
#pragma unroll
      for (int j = 0; j < 8; ++j)
#pragma unroll
        for (int r = 0; r < 4; ++r)
          of[i][j][r] *= a;
#pragma unroll
      for (int r = 0; r < 4; ++r) ofl[i][r] *= a;
#pragma unroll
      for (int j = 0; j < 4; ++j)
#pragma unroll
        for (int r = 0; r < 4; ++r)
          st[i][j][r] = __builtin_amdgcn_exp2f(st[i][j][r] - mn);
    }

#pragma unroll
    for (int i = 0; i < 2; ++i)
#pragma unroll
      for (int j = 0; j < 4; ++j)
        *(vshort4*)(pw + (i * 16 + c16) * 72 + j * 16 + q4 * 4) =
            pack4f(st[i][j][0], st[i][j][1], st[i][j][2], st[i][j][3]);

    __builtin_amdgcn_s_setprio(1);
#pragma unroll
    for (int kk = 0; kk < 2; ++kk) {
      vbf16x8 p0 = ld_frag(pw + (c16) * 72 + kk * 32 + q4 * 8);
      vbf16x8 p1 = ld_frag(pw + (16 + c16) * 72 + kk * 32 + q4 * 8);
#pragma unroll
      for (int jd = 0; jd < 8; ++jd) {
        vbf16x8 vf = ld_frag(kvV + (jd * 16 + c16) * 72 + kk * 32 + q4 * 8);
        of[0][jd] = mfma16(vf, p0, of[0][jd]);
        of[1][jd] = mfma16(vf, p1, of[1][jd]);
      }
      ofl[0] = mfma16(onesf, p0, ofl[0]);
      ofl[1] = mfma16(onesf, p1, ofl[1]);
    }
    __builtin_amdgcn_s_setprio(0);
  }

#pragma unroll
  for (int i = 0; i < 2; ++i) {
    int lr = w * 32 + i * 16 + c16;
    int qrow = q0 + lr;
    float l = ofl[i][0];
    if (chunk < 0) {
      float inv_l = 1.f / l;
#pragma unroll
      for (int jd = 0; jd < 8; ++jd)
        *(vshort4*)(attnb + (size_t)qrow * QSZ + h * HD + jd * 16 + q4 * 4) =
            pack4f(of[i][jd][0] * inv_l, of[i][jd][1] * inv_l,
                   of[i][jd][2] * inv_l, of[i][jd][3] * inv_l);
    } else if (chunk == 0) {
#pragma unroll
      for (int jd = 0; jd < 8; ++jd)
        *(vshort4*)(attnb + (size_t)qrow * QSZ + h * HD + jd * 16 + q4 * 4) =
            pack4f(of[i][jd][0], of[i][jd][1], of[i][jd][2], of[i][jd][3]);
      if (q4 == 0) { ml[t * 512 + lr * 4 + 0] = m_run[i]; ml[t * 512 + lr * 4 + 1] = l; }
    } else {
#pragma unroll
      for (int jd = 0; jd < 8; ++jd)
        *(vshort4*)(part1 + (size_t)t * 16384 + lr * 128 + jd * 16 + q4 * 4) =
            pack4f(of[i][jd][0], of[i][jd][1], of[i][jd][2], of[i][jd][3]);
      if (q4 == 0) { ml[t * 512 + lr * 4 + 2] = m_run[i]; ml[t * 512 + lr * 4 + 3] = l; }
    }
  }
}

// ---------------------------------------------------------------------------
// NOTE: ml stores running max in exp2 (log2) domain -> combine uses exp2.
// ---------------------------------------------------------------------------
__global__ __launch_bounds__(256) void combine_kernel(
    unsigned short* __restrict__ attnb, const unsigned short* __restrict__ part1,
    const float* __restrict__ ml)
{
  int t = blockIdx.x;
  int h = t >> 3, qt = (t & 7) + 8;
  int lr = threadIdx.x >> 1, ch = (threadIdx.x & 1) * 64;
  int row = qt * 128 + lr;
  float m0 = ml[t * 512 + lr * 4 + 0], l0 = ml[t * 512 + lr * 4 + 1];
  float m1 = ml[t * 512 + lr * 4 + 2], l1 = ml[t * 512 + lr * 4 + 3];
  float M = fmaxf(m0, m1);
  float w0 = __builtin_amdgcn_exp2f(m0 - M), w1 = __builtin_amdgcn_exp2f(m1 - M);
  float inv = 1.f / (l0 * w0 + l1 * w1);
  unsigned short* dst = attnb + (size_t)row * QSZ + h * HD + ch;
  const unsigned short* src = part1 + (size_t)t * 16384 + lr * 128 + ch;
#pragma unroll
  for (int k = 0; k < 8; ++k) {
    vshort8 a = *(const vshort8*)(dst + k * 8);
    vshort8 b = *(const vshort8*)(src + k * 8);
    vshort8 o;
#pragma unroll
    for (int jj = 0; jj < 8; ++jj)
      o[jj] = (short)f2bf((bf2f((unsigned short)a[jj]) * w0 +
                           bf2f((unsigned short)b[jj]) * w1) * inv);
    *(vshort8*)(dst + k * 8) = o;
  }
}

// ---------------------------------------------------------------------------
extern "C" void kernel_launch(void* const* d_in, const int* in_sizes, int n_in,
                              void* d_out, int out_size, void* d_ws, size_t ws_size,
                              hipStream_t stream)
{
  const void* hidden = d_in[0];
  const int*  pos    = (const int*)d_in[1];
  const int*  qkv_qw = (const int*)d_in[2];
  const int*  qkv_qz = (const int*)d_in[3];
  const void* qkv_sc = d_in[4];
  const void* qkv_bs = d_in[5];
  const int*  o_qw   = (const int*)d_in[6];
  const int*  o_qz   = (const int*)d_in[7];
  const void* o_sc   = d_in[8];

  char* ws = (char*)d_ws;
  unsigned short* hidbf = (unsigned short*)d_out;  // dead once gemm1 done

  if (ws_size >= 67052560ULL) {
    // ------- big layout: single-launch GEMMs -------
    unsigned short* qkvb   = (unsigned short*)ws;               // [2048][4608]
    unsigned short* attnb  = (unsigned short*)(ws + 18874368);  // [2048][3584]
    unsigned short* W      = (unsigned short*)(ws + 33554432);  // weights 33 MB
    unsigned short* part1  = W;                                  // after gemm1
    float*          mlbuf  = (float*)(ws + 33554432 + 7340032);
    float2*         tbl    = (float2*)(ws + 41943040);           // 1 MB, rope only
    unsigned short* VtBuf  = (unsigned short*)(ws + 44040192);   // 2 MB, attn only
    unsigned short* scbf1  = (unsigned short*)(ws + 66584576);
    unsigned short* scbf2  = (unsigned short*)(ws + 66842624);
    unsigned short* biasbf = (unsigned short*)(ws + 67043328);
    int*            flag   = (int*)(ws + 67052544);

    detect_dtype<<<1, 256, 0, stream>>>((const unsigned short*)hidden, flag);
    convert_bf8<<<3584, 256, 0, stream>>>(hidden, hidbf, flag);
    convert_bf8<<<63, 256, 0, stream>>>(qkv_sc, scbf1, flag);
    convert_bf<<<18, 256, 0, stream>>>(qkv_bs, biasbf, flag);
    convert_bf8<<<49, 256, 0, stream>>>(o_sc, scbf2, flag);

    dequant_awq<<<2016, 256, 0, stream>>>(qkv_qw, qkv_qz, scbf1, W, 3584, 576, 576, 4608);
    gemm8p<192><<<dim3(24, 8), 512, 0, stream>>>(hidbf, W, biasbf, qkvb, 0, 4608, 3584, nullptr);
    vt_kernel<<<dim3(32, 8), 256, 0, stream>>>(qkvb, VtBuf);
    rope_table<<<512, 256, 0, stream>>>(pos, tbl);
    rope_apply<<<4096, 256, 0, stream>>>(qkvb, tbl);
    attn_kernel<<<672, 256, 0, stream>>>(qkvb, VtBuf, attnb, part1, mlbuf);
    combine_kernel<<<224, 256, 0, stream>>>(attnb, part1, mlbuf);
    dequant_awq<<<1568, 256, 0, stream>>>(o_qw, o_qz, scbf2, W, 3584, 448, 448, 3584);
    gemm8p<128><<<dim3(28, 8), 512, 0, stream>>>(attnb, W, nullptr, d_out, 0, 3584, 3584, flag);
  } else {
    // ------- chunked fallback (known-safe 43.7 MB) -------
    unsigned short* qkvb   = (unsigned short*)ws;               // [2048][4608]
    unsigned short* attnb  = (unsigned short*)(ws + 18874368);  // [2048][3584]
    unsigned short* wscr1  = attnb;                             // [2304][3584]
    float2*         tbl    = (float2*)(ws + 18874368);          // rope only
    unsigned short* part1  = (unsigned short*)(ws + 35389440);  // [224][16384]
    float*          mlbuf  = (float*)(ws + 42729472);           // [224][512]
    int*            flag   = (int*)(ws + 43188224);
    unsigned short* scbf1  = (unsigned short*)(ws + 43188240);
    unsigned short* scbf2  = (unsigned short*)(ws + 43446288);
    unsigned short* biasbf = (unsigned short*)(ws + 43646992);
    unsigned short* wscr2  = qkvb;

    detect_dtype<<<1, 256, 0, stream>>>((const unsigned short*)hidden, flag);
    convert_bf8<<<3584, 256, 0, stream>>>(hidden, hidbf, flag);
    convert_bf8<<<63, 256, 0, stream>>>(qkv_sc, scbf1, flag);
    convert_bf<<<18, 256, 0, stream>>>(qkv_bs, biasbf, flag);
    convert_bf8<<<49, 256, 0, stream>>>(o_sc, scbf2, flag);

    for (int c = 0; c < 2; ++c) {
      dequant_awq<<<1008, 256, 0, stream>>>(
          qkv_qw + c * 288, qkv_qz + c * 288, scbf1 + c * 2304, wscr1,
          3584, 288, 576, 4608);
      gemm8p<192><<<dim3(12, 8), 512, 0, stream>>>(
          hidbf, wscr1, biasbf + c * 2304, qkvb, c * 2304, 4608, 3584, nullptr);
    }
    rope_table<<<512, 256, 0, stream>>>(pos, tbl);
    rope_apply<<<4096, 256, 0, stream>>>(qkvb, tbl);
    attn_kernel_lds<<<672, 256, 0, stream>>>(qkvb, attnb, part1, mlbuf);
    combine_kernel<<<224, 256, 0, stream>>>(attnb, part1, mlbuf);
    for (int c = 0; c < 2; ++c) {
      dequant_awq<<<784, 256, 0, stream>>>(
          o_qw + c * 224, o_qz + c * 224, scbf2 + c * 1792, wscr2,
          3584, 224, 448, 3584);
      gemm8p<128><<<dim3(14, 8), 512, 0, stream>>>(
          attnb, wscr2, nullptr, d_out, c * 1792, 3584, 3584, flag);
    }
  }
}